// Round 7
// baseline (1083.040 us; speedup 1.0000x reference)
//
#include <hip/hip_runtime.h>

typedef __attribute__((ext_vector_type(8))) short bf16x8;
typedef __attribute__((ext_vector_type(4))) float f32x4;
typedef __attribute__((ext_vector_type(4))) unsigned int u32x4;

union UB8 { bf16x8 v; unsigned d[4]; unsigned short u[8]; };

__device__ __forceinline__ float bf2f(unsigned short u) {
  union { unsigned u; float f; } a; a.u = ((unsigned)u) << 16;
  return a.f;
}
// native cast -> v_cvt_pk_bf16_f32 (RNE)
__device__ __forceinline__ unsigned pk2bf(float lo, float hi) {
  union { __bf16 b[2]; unsigned u; } r;
  r.b[0] = (__bf16)lo; r.b[1] = (__bf16)hi;
  return r.u;
}
__device__ __forceinline__ unsigned short f2bf(float f) {  // prep only
  union { float f; unsigned u; } a; a.f = f;
  return (unsigned short)((a.u + 0x7fffu + ((a.u >> 16) & 1u)) >> 16);
}

// ======================= prep kernel =======================
// Builds a 103424-byte image in ws that the main kernel copies linearly to LDS:
//   bytes [0, 98304):   384 rows x 256B bf16 weights, row-swizzled byte = (2c)^((r&7)<<4)
//     rows   0.. 63 : Wq, ROW-permuted  r'(h,d): t = 16*(d%8>=4) + 4*(d/8) + (d%4)... (see below)
//     rows  64..127 : Wk, same row-perm
//     rows 128..255 : Wv, natural rows
//     rows 256..383 : Wo, natural rows
//     ALL rows col-permuted: image col cp=32ks+8kg+jj <- src col 4kg+16*(2ks+(jj>=4))+(jj&3)
//   bytes [98304,102400): PE f32[8][128], float idx col^(r<<2) swizzle
//   bytes [102400,103424): gamma f32[128], beta f32[128]
// Row-perm (Q/K): permuted within-head index t=16a+4kg+j2 holds orig dim d=8kg+4a+j2,
// so QKV MFMA outputs (4 feats/lane-quad) ARE the S-MFMA fragments (zero shuffles).
__global__ __launch_bounds__(1024)
void prep_kernel(const float* __restrict__ Wq, const float* __restrict__ Wk,
                 const float* __restrict__ Wv, const float* __restrict__ Wo,
                 const float* __restrict__ gamma, const float* __restrict__ beta,
                 unsigned short* __restrict__ ws) {
  const int i = blockIdx.x * 1024 + threadIdx.x;
  if (i < 49152) {
    const int r = i >> 7, cp = i & 127;
    const int ks = cp >> 5, kg = (cp >> 3) & 3, jj = cp & 7;
    const int sc = 4 * kg + 16 * (2 * ks + (jj >> 2)) + (jj & 3);  // src col
    float v;
    if (r < 128) {
      const int blk = r >> 6;          // 0=Q, 1=K
      const int rb = r & 63;
      const int h = rb >> 5, tt = rb & 31;
      const int d = 8 * ((tt >> 2) & 3) + 4 * (tt >> 4) + (tt & 3); // src dim
      const float* W = blk ? Wk : Wq;
      v = W[(h * 32 + d) * 128 + sc];
    } else if (r < 256) {
      v = Wv[(r - 128) * 128 + sc];
    } else {
      v = Wo[(r - 256) * 128 + sc];
    }
    const int byte = r * 256 + ((cp * 2) ^ ((r & 7) << 4));
    *(unsigned short*)((char*)ws + byte) = f2bf(v);
  } else if (i < 50176) {
    const int e = i - 49152;           // 0..1023
    const int r = e >> 7, col = e & 127;
    const float div = expf(-0.14391156831212727f * (float)(col >> 1));
    const float ang = (float)r * div;
    float* pe = (float*)(ws + 49152);
    pe[r * 128 + (col ^ (r << 2))] = (col & 1) ? cosf(ang) : sinf(ang);
  } else if (i < 50432) {
    const int e = i - 50176;           // 0..255: gamma then beta
    float* gb = (float*)(ws + 49152);
    gb[1024 + e] = (e < 128) ? gamma[e] : beta[e - 128];
  }
}

// ======================= fused kernel =======================
// 1024 threads = 16 waves; 1 block/CU (LDS 103424B); 256 blocks.
// Each wave independently processes 8 pairs of batch rows (2 rows = 16 chunk-rows
// = one full MFMA M). NO __syncthreads after the one-time weight staging: waves
// drift freely, overlapping HBM bursts with compute. All intermediates in VGPRs;
// LDS is read-only (weights/PE/gamma-beta).
__global__ __launch_bounds__(1024, 4)
void wlmha_kernel(const float* __restrict__ x,
                  const unsigned short* __restrict__ wsg,
                  const float* __restrict__ relb,
                  float* __restrict__ y_out,
                  float* __restrict__ attn_out)
{
  __shared__ __align__(16) char smem[103424];
  const int t = threadIdx.x;

  // one-time stage: 103424 B = 6464 x 16B
  {
    const u32x4* src = (const u32x4*)wsg;
    u32x4* dst = (u32x4*)smem;
    for (int i = t; i < 6464; i += 1024) dst[i] = src[i];
  }
  __syncthreads();

  const char*  wS  = smem;                          // [384][256B] swizzled bf16
  const float* peS = (const float*)(smem + 98304);  // [8][128] f32 swizzled
  const float* gbS = (const float*)(smem + 102400); // gamma[128], beta[128]

  const int l  = t & 63;
  const int wv = t >> 6;          // wave 0..15
  const int c  = l & 15;          // lane's chunk-row / q-row / vfeat-row
  const int kg = l >> 4;          // lane quad 0..3
  const int c7 = c & 7;
  const int swz = c7 << 4;

  // rel-pos bias (8 scalars, L2-hot), mask, shuffle base — loop-invariant
  float biasr[2][4];
#pragma unroll
  for (int h = 0; h < 2; ++h)
#pragma unroll
    for (int j = 0; j < 4; ++j)
      biasr[h][j] = relb[h * 15 + ((kg & 1) * 4 + j) - c7 + 7];
  const bool vmask = ((l >> 5) & 1) == ((l >> 3) & 1);
  const int sA = c + ((kg & 1) << 5);   // shuffle src for 4->8 key regroup

  for (int it = 0; it < 8; ++it) {
    const size_t pair = ((size_t)blockIdx.x * 16 + wv) * 8 + it;
    const float* xb = x + pair * 2048;

    // ---- x + pe -> xc A-frags (regs). Lane (c,kg) holds feats 4kg+16m+j. ----
    f32x4 xq[8];
#pragma unroll
    for (int m = 0; m < 8; ++m)
      xq[m] = *(const f32x4*)(xb + c * 128 + kg * 4 + m * 16);
#pragma unroll
    for (int m = 0; m < 8; ++m) {
      const f32x4 pv = *(const f32x4*)(peS + c7 * 128 + ((kg * 4 + m * 16) ^ (c7 * 4)));
      xq[m] += pv;
    }
    UB8 xcf[4];
#pragma unroll
    for (int ks = 0; ks < 4; ++ks) {
      xcf[ks].d[0] = pk2bf(xq[2 * ks][0], xq[2 * ks][1]);
      xcf[ks].d[1] = pk2bf(xq[2 * ks][2], xq[2 * ks][3]);
      xcf[ks].d[2] = pk2bf(xq[2 * ks + 1][0], xq[2 * ks + 1][1]);
      xcf[ks].d[3] = pk2bf(xq[2 * ks + 1][2], xq[2 * ks + 1][3]);
    }

    // ---- QKV: 16 groups x (4 ds_read + 4 MFMA). Q|K: mfma(W,xc) -> lane(chunk, feats);
    //      V: mfma(xc,W) -> lane(vfeat, keys). Outputs packed bf16 in regs. ----
    unsigned qk[8][2], vv[8][2];
#pragma unroll
    for (int nb = 0; nb < 16; ++nb) {
      bf16x8 wf[4];
#pragma unroll
      for (int ks = 0; ks < 4; ++ks)
        wf[ks] = *(const bf16x8*)(wS + (nb * 16 + c) * 256 + ((ks * 64 + kg * 16) ^ swz));
      f32x4 acc = {0.f, 0.f, 0.f, 0.f};
      if (nb < 8) {
#pragma unroll
        for (int ks = 0; ks < 4; ++ks)
          acc = __builtin_amdgcn_mfma_f32_16x16x32_bf16(wf[ks], xcf[ks].v, acc, 0, 0, 0);
        qk[nb][0] = pk2bf(acc[0], acc[1]);
        qk[nb][1] = pk2bf(acc[2], acc[3]);
      } else {
#pragma unroll
        for (int ks = 0; ks < 4; ++ks)
          acc = __builtin_amdgcn_mfma_f32_16x16x32_bf16(xcf[ks].v, wf[ks], acc, 0, 0, 0);
        vv[nb - 8][0] = pk2bf(acc[0], acc[1]);
        vv[nb - 8][1] = pk2bf(acc[2], acc[3]);
      }
    }

    // ---- attention per head: S^T = mfma(K,Q) (frags are direct regs thanks to
    //      the row-perm), masked softmax, PV via 4->8 shuffled V/P frags. ----
    unsigned ctx[8][2];
    const long B0 = (long)pair * 2;
#pragma unroll
    for (int h = 0; h < 2; ++h) {
      UB8 qf, kf;
      qf.d[0] = qk[2 * h][0];     qf.d[1] = qk[2 * h][1];
      qf.d[2] = qk[2 * h + 1][0]; qf.d[3] = qk[2 * h + 1][1];
      kf.d[0] = qk[4 + 2 * h][0];     kf.d[1] = qk[4 + 2 * h][1];
      kf.d[2] = qk[4 + 2 * h + 1][0]; kf.d[3] = qk[4 + 2 * h + 1][1];
      const f32x4 zero = {0.f, 0.f, 0.f, 0.f};
      const f32x4 st = __builtin_amdgcn_mfma_f32_16x16x32_bf16(kf.v, qf.v, zero, 0, 0, 0);
      float s0[4];
#pragma unroll
      for (int j = 0; j < 4; ++j)
        s0[j] = vmask ? st[j] * 0.17677669529663687f + biasr[h][j] : -1e30f;
      float mx = fmaxf(fmaxf(s0[0], s0[1]), fmaxf(s0[2], s0[3]));
      mx = fmaxf(mx, __shfl_xor(mx, 16));
      mx = fmaxf(mx, __shfl_xor(mx, 32));
      float p[4], sum = 0.f;
#pragma unroll
      for (int j = 0; j < 4; ++j) { p[j] = __expf(s0[j] - mx); sum += p[j]; }
      sum += __shfl_xor(sum, 16);
      sum += __shfl_xor(sum, 32);
      const float inv = 1.0f / sum;
#pragma unroll
      for (int j = 0; j < 4; ++j) p[j] *= inv;

      if (vmask) {
        float* ap = attn_out + ((B0 + (c >> 3)) * 2 + h) * 64 + c7 * 8 + (kg & 1) * 4;
        const f32x4 pv = {p[0], p[1], p[2], p[3]};
        *(f32x4*)ap = pv;
      }

      // P^T B-frag: keys 8kg+jj (kg 0,1 real; 2,3 zero)
      const unsigned P0 = pk2bf(p[0], p[1]);
      const unsigned P1 = pk2bf(p[2], p[3]);
      UB8 pf;
      pf.d[0] = (unsigned)__shfl((int)P0, sA);
      pf.d[1] = (unsigned)__shfl((int)P1, sA);
      pf.d[2] = (unsigned)__shfl((int)P0, sA + 16);
      pf.d[3] = (unsigned)__shfl((int)P1, sA + 16);
      if (kg >= 2) { pf.d[0] = 0; pf.d[1] = 0; pf.d[2] = 0; pf.d[3] = 0; }

      // ctx^T = mfma(Vt, P^T) per 16-vfeat group; Vt frag = same 4->8 regroup of vv
#pragma unroll
      for (int vb = 0; vb < 4; ++vb) {
        UB8 vt;
        vt.d[0] = (unsigned)__shfl((int)vv[4 * h + vb][0], sA);
        vt.d[1] = (unsigned)__shfl((int)vv[4 * h + vb][1], sA);
        vt.d[2] = (unsigned)__shfl((int)vv[4 * h + vb][0], sA + 16);
        vt.d[3] = (unsigned)__shfl((int)vv[4 * h + vb][1], sA + 16);
        if (kg >= 2) { vt.d[0] = 0; vt.d[1] = 0; vt.d[2] = 0; vt.d[3] = 0; }
        const f32x4 cacc = __builtin_amdgcn_mfma_f32_16x16x32_bf16(vt.v, pf.v, zero, 0, 0, 0);
        ctx[4 * h + vb][0] = pk2bf(cacc[0], cacc[1]);
        ctx[4 * h + vb][1] = pk2bf(cacc[2], cacc[3]);
      }
    }

    // ---- out-proj: cf B-frags are direct ctx regs (Wo col-perm absorbs layout) ----
    UB8 cf[4];
#pragma unroll
    for (int ks = 0; ks < 4; ++ks) {
      cf[ks].d[0] = ctx[2 * ks][0];
      cf[ks].d[1] = ctx[2 * ks][1];
      cf[ks].d[2] = ctx[2 * ks + 1][0];
      cf[ks].d[3] = ctx[2 * ks + 1][1];
    }
    f32x4 hacc[8];
#pragma unroll
    for (int nt = 0; nt < 8; ++nt) {
      bf16x8 wof[4];
#pragma unroll
      for (int ks = 0; ks < 4; ++ks)
        wof[ks] = *(const bf16x8*)(wS + (256 + nt * 16 + c) * 256 + ((ks * 64 + kg * 16) ^ swz));
      f32x4 acc = {0.f, 0.f, 0.f, 0.f};
#pragma unroll
      for (int ks = 0; ks < 4; ++ks)
        acc = __builtin_amdgcn_mfma_f32_16x16x32_bf16(wof[ks], cf[ks].v, acc, 0, 0, 0);
      hacc[nt] = acc;   // lane (q=c, kg): out feats 16nt+4kg+j
    }

    // ---- residual (lane-local from xcf!) + LN + y store ----
    float sum = 0.f, sq = 0.f;
#pragma unroll
    for (int nt = 0; nt < 8; ++nt) {
      UB8 xr; xr.v = xcf[nt >> 1].v;
      const int base = 4 * (nt & 1);
#pragma unroll
      for (int j = 0; j < 4; ++j) {
        const float hv = hacc[nt][j] + bf2f(xr.u[base + j]);
        hacc[nt][j] = hv;
        sum += hv; sq += hv * hv;
      }
    }
    sum += __shfl_xor(sum, 16); sq += __shfl_xor(sq, 16);
    sum += __shfl_xor(sum, 32); sq += __shfl_xor(sq, 32);
    const float mu = sum * 0.0078125f;
    const float rs = rsqrtf(sq * 0.0078125f - mu * mu + 1e-5f);
    float* yb = y_out + pair * 2048;
#pragma unroll
    for (int nt = 0; nt < 8; ++nt) {
      const f32x4 g = *(const f32x4*)(gbS + 16 * nt + 4 * kg);
      const f32x4 b = *(const f32x4*)(gbS + 128 + 16 * nt + 4 * kg);
      f32x4 o;
#pragma unroll
      for (int j = 0; j < 4; ++j)
        o[j] = (hacc[nt][j] - mu) * rs * g[j] + b[j];
      *(f32x4*)(yb + c * 128 + 16 * nt + 4 * kg) = o;
    }
  }
}

extern "C" void kernel_launch(void* const* d_in, const int* in_sizes, int n_in,
                              void* d_out, int out_size, void* d_ws, size_t ws_size,
                              hipStream_t stream) {
  (void)in_sizes; (void)n_in; (void)out_size; (void)ws_size;
  const float* x    = (const float*)d_in[0];
  const float* Wq   = (const float*)d_in[1];
  const float* Wk   = (const float*)d_in[2];
  const float* Wv   = (const float*)d_in[3];
  const float* Wo   = (const float*)d_in[4];
  const float* gam  = (const float*)d_in[5];
  const float* bet  = (const float*)d_in[6];
  const float* relb = (const float*)d_in[7];
  float* y    = (float*)d_out;
  float* attn = y + (size_t)65536 * 1024;
  unsigned short* ws = (unsigned short*)d_ws;

  hipLaunchKernelGGL(prep_kernel, dim3(50), dim3(1024), 0, stream,
                     Wq, Wk, Wv, Wo, gam, bet, ws);
  hipLaunchKernelGGL(wlmha_kernel, dim3(256), dim3(1024), 0, stream,
                     x, ws, relb, y, attn);
}

// Round 8
// 1082.413 us; speedup vs baseline: 1.0006x; 1.0006x over previous
//
#include <hip/hip_runtime.h>

typedef __attribute__((ext_vector_type(8))) short bf16x8;
typedef __attribute__((ext_vector_type(4))) float f32x4;
typedef __attribute__((ext_vector_type(4))) unsigned int u32x4;

union UB8 { bf16x8 v; unsigned d[4]; unsigned short u[8]; };

__device__ __forceinline__ float bf2f(unsigned short u) {
  union { unsigned u; float f; } a; a.u = ((unsigned)u) << 16;
  return a.f;
}
// native cast -> v_cvt_pk_bf16_f32 (RNE)
__device__ __forceinline__ unsigned pk2bf(float lo, float hi) {
  union { __bf16 b[2]; unsigned u; } r;
  r.b[0] = (__bf16)lo; r.b[1] = (__bf16)hi;
  return r.u;
}
__device__ __forceinline__ unsigned short f2bf(float f) {  // prep only
  union { float f; unsigned u; } a; a.f = f;
  return (unsigned short)((a.u + 0x7fffu + ((a.u >> 16) & 1u)) >> 16);
}

// ======================= prep kernel (unchanged from r7 — validated) =======================
// Builds a 103424-byte image in ws that the main kernel copies linearly to LDS:
//   bytes [0, 98304):   384 rows x 256B bf16 weights, row-swizzled byte = (2c)^((r&7)<<4)
//     rows 0..63 Wq (row-permuted), 64..127 Wk (row-permuted), 128..255 Wv, 256..383 Wo
//     all rows col-permuted: image col cp=32ks+8kg+jj <- src col 4kg+16*(2ks+(jj>=4))+(jj&3)
//   bytes [98304,102400): PE f32[8][128], col^(r<<2) swizzle
//   bytes [102400,103424): gamma f32[128], beta f32[128]
__global__ __launch_bounds__(1024)
void prep_kernel(const float* __restrict__ Wq, const float* __restrict__ Wk,
                 const float* __restrict__ Wv, const float* __restrict__ Wo,
                 const float* __restrict__ gamma, const float* __restrict__ beta,
                 unsigned short* __restrict__ ws) {
  const int i = blockIdx.x * 1024 + threadIdx.x;
  if (i < 49152) {
    const int r = i >> 7, cp = i & 127;
    const int ks = cp >> 5, kg = (cp >> 3) & 3, jj = cp & 7;
    const int sc = 4 * kg + 16 * (2 * ks + (jj >> 2)) + (jj & 3);  // src col
    float v;
    if (r < 128) {
      const int blk = r >> 6;          // 0=Q, 1=K
      const int rb = r & 63;
      const int h = rb >> 5, tt = rb & 31;
      const int d = 8 * ((tt >> 2) & 3) + 4 * (tt >> 4) + (tt & 3); // src dim
      const float* W = blk ? Wk : Wq;
      v = W[(h * 32 + d) * 128 + sc];
    } else if (r < 256) {
      v = Wv[(r - 128) * 128 + sc];
    } else {
      v = Wo[(r - 256) * 128 + sc];
    }
    const int byte = r * 256 + ((cp * 2) ^ ((r & 7) << 4));
    *(unsigned short*)((char*)ws + byte) = f2bf(v);
  } else if (i < 50176) {
    const int e = i - 49152;           // 0..1023
    const int r = e >> 7, col = e & 127;
    const float div = expf(-0.14391156831212727f * (float)(col >> 1));
    const float ang = (float)r * div;
    float* pe = (float*)(ws + 49152);
    pe[r * 128 + (col ^ (r << 2))] = (col & 1) ? cosf(ang) : sinf(ang);
  } else if (i < 50432) {
    const int e = i - 50176;           // 0..255: gamma then beta
    float* gb = (float*)(ws + 49152);
    gb[1024 + e] = (e < 128) ? gamma[e] : beta[e - 128];
  }
}

// ======================= fused kernel =======================
// 1024 threads = 16 waves; 1 block/CU (LDS 103424B); 256 blocks; no barriers in loop.
// amdgpu_waves_per_eu(4,4): LDS caps us at 1 block/CU = 16 waves = 4/EU anyway, so
// pin the allocator at 4 waves/EU -> full 128-VGPR budget, no squeeze (r7: squeezed
// to 64 + spilled 2.5GB of scratch). Peak live state kept <= ~100 VGPR by packing
// post-out-proj h to bf16 (16 regs) with f32 LN sums accumulated inline.
__global__ __launch_bounds__(1024) __attribute__((amdgpu_waves_per_eu(4, 4)))
void wlmha_kernel(const float* __restrict__ x,
                  const unsigned short* __restrict__ wsg,
                  const float* __restrict__ relb,
                  float* __restrict__ y_out,
                  float* __restrict__ attn_out)
{
  __shared__ __align__(16) char smem[103424];
  const int t = threadIdx.x;

  // one-time stage: 103424 B = 6464 x 16B
  {
    const u32x4* src = (const u32x4*)wsg;
    u32x4* dst = (u32x4*)smem;
    for (int i = t; i < 6464; i += 1024) dst[i] = src[i];
  }
  __syncthreads();

  const char*  wS  = smem;                          // [384][256B] swizzled bf16
  const float* peS = (const float*)(smem + 98304);  // [8][128] f32 swizzled
  const float* gbS = (const float*)(smem + 102400); // gamma[128], beta[128]

  const int l  = t & 63;
  const int wv = t >> 6;          // wave 0..15
  const int c  = l & 15;          // lane's chunk-row / q-row / vfeat-row
  const int kg = l >> 4;          // lane quad 0..3
  const int c7 = c & 7;
  const int swz = c7 << 4;

  float biasr[2][4];
#pragma unroll
  for (int h = 0; h < 2; ++h)
#pragma unroll
    for (int j = 0; j < 4; ++j)
      biasr[h][j] = relb[h * 15 + ((kg & 1) * 4 + j) - c7 + 7];
  const bool vmask = ((l >> 5) & 1) == ((l >> 3) & 1);
  const int sA = c + ((kg & 1) << 5);   // shuffle src for 4->8 key regroup

  for (int it = 0; it < 8; ++it) {
    const size_t pair = ((size_t)blockIdx.x * 16 + wv) * 8 + it;
    const float* xb = x + pair * 2048;

    // ---- x + pe -> xc A-frags. xq dies after packing (transient 32 regs). ----
    UB8 xcf[4];
    {
      f32x4 xq[8];
#pragma unroll
      for (int m = 0; m < 8; ++m)
        xq[m] = *(const f32x4*)(xb + c * 128 + kg * 4 + m * 16);
#pragma unroll
      for (int m = 0; m < 8; ++m) {
        const f32x4 pv = *(const f32x4*)(peS + c7 * 128 + ((kg * 4 + m * 16) ^ (c7 * 4)));
        xq[m] += pv;
      }
#pragma unroll
      for (int ks = 0; ks < 4; ++ks) {
        xcf[ks].d[0] = pk2bf(xq[2 * ks][0], xq[2 * ks][1]);
        xcf[ks].d[1] = pk2bf(xq[2 * ks][2], xq[2 * ks][3]);
        xcf[ks].d[2] = pk2bf(xq[2 * ks + 1][0], xq[2 * ks + 1][1]);
        xcf[ks].d[3] = pk2bf(xq[2 * ks + 1][2], xq[2 * ks + 1][3]);
      }
    }

    // ---- QKV: 16 groups x (4 ds_read_b128 + 4 MFMA), outputs packed bf16 regs ----
    unsigned qk[8][2], vv[8][2];
#pragma unroll
    for (int nb = 0; nb < 16; ++nb) {
      bf16x8 wf[4];
#pragma unroll
      for (int ks = 0; ks < 4; ++ks)
        wf[ks] = *(const bf16x8*)(wS + (nb * 16 + c) * 256 + ((ks * 64 + kg * 16) ^ swz));
      f32x4 acc = {0.f, 0.f, 0.f, 0.f};
      if (nb < 8) {
#pragma unroll
        for (int ks = 0; ks < 4; ++ks)
          acc = __builtin_amdgcn_mfma_f32_16x16x32_bf16(wf[ks], xcf[ks].v, acc, 0, 0, 0);
        qk[nb][0] = pk2bf(acc[0], acc[1]);
        qk[nb][1] = pk2bf(acc[2], acc[3]);
      } else {
#pragma unroll
        for (int ks = 0; ks < 4; ++ks)
          acc = __builtin_amdgcn_mfma_f32_16x16x32_bf16(xcf[ks].v, wf[ks], acc, 0, 0, 0);
        vv[nb - 8][0] = pk2bf(acc[0], acc[1]);
        vv[nb - 8][1] = pk2bf(acc[2], acc[3]);
      }
    }

    // ---- attention per head (swapped S^T, frags direct from regs) ----
    unsigned ctx[8][2];
    const long B0 = (long)pair * 2;
#pragma unroll
    for (int h = 0; h < 2; ++h) {
      UB8 qf, kf;
      qf.d[0] = qk[2 * h][0];     qf.d[1] = qk[2 * h][1];
      qf.d[2] = qk[2 * h + 1][0]; qf.d[3] = qk[2 * h + 1][1];
      kf.d[0] = qk[4 + 2 * h][0];     kf.d[1] = qk[4 + 2 * h][1];
      kf.d[2] = qk[4 + 2 * h + 1][0]; kf.d[3] = qk[4 + 2 * h + 1][1];
      const f32x4 zero = {0.f, 0.f, 0.f, 0.f};
      const f32x4 st = __builtin_amdgcn_mfma_f32_16x16x32_bf16(kf.v, qf.v, zero, 0, 0, 0);
      float s0[4];
#pragma unroll
      for (int j = 0; j < 4; ++j)
        s0[j] = vmask ? st[j] * 0.17677669529663687f + biasr[h][j] : -1e30f;
      float mx = fmaxf(fmaxf(s0[0], s0[1]), fmaxf(s0[2], s0[3]));
      mx = fmaxf(mx, __shfl_xor(mx, 16));
      mx = fmaxf(mx, __shfl_xor(mx, 32));
      float p[4], sum = 0.f;
#pragma unroll
      for (int j = 0; j < 4; ++j) { p[j] = __expf(s0[j] - mx); sum += p[j]; }
      sum += __shfl_xor(sum, 16);
      sum += __shfl_xor(sum, 32);
      const float inv = 1.0f / sum;
#pragma unroll
      for (int j = 0; j < 4; ++j) p[j] *= inv;

      if (vmask) {
        float* ap = attn_out + ((B0 + (c >> 3)) * 2 + h) * 64 + c7 * 8 + (kg & 1) * 4;
        const f32x4 pv = {p[0], p[1], p[2], p[3]};
        *(f32x4*)ap = pv;
      }

      const unsigned P0 = pk2bf(p[0], p[1]);
      const unsigned P1 = pk2bf(p[2], p[3]);
      UB8 pf;
      pf.d[0] = (unsigned)__shfl((int)P0, sA);
      pf.d[1] = (unsigned)__shfl((int)P1, sA);
      pf.d[2] = (unsigned)__shfl((int)P0, sA + 16);
      pf.d[3] = (unsigned)__shfl((int)P1, sA + 16);
      if (kg >= 2) { pf.d[0] = 0; pf.d[1] = 0; pf.d[2] = 0; pf.d[3] = 0; }

#pragma unroll
      for (int vb = 0; vb < 4; ++vb) {
        UB8 vt;
        vt.d[0] = (unsigned)__shfl((int)vv[4 * h + vb][0], sA);
        vt.d[1] = (unsigned)__shfl((int)vv[4 * h + vb][1], sA);
        vt.d[2] = (unsigned)__shfl((int)vv[4 * h + vb][0], sA + 16);
        vt.d[3] = (unsigned)__shfl((int)vv[4 * h + vb][1], sA + 16);
        if (kg >= 2) { vt.d[0] = 0; vt.d[1] = 0; vt.d[2] = 0; vt.d[3] = 0; }
        const f32x4 cacc = __builtin_amdgcn_mfma_f32_16x16x32_bf16(vt.v, pf.v, zero, 0, 0, 0);
        ctx[4 * h + vb][0] = pk2bf(cacc[0], cacc[1]);
        ctx[4 * h + vb][1] = pk2bf(cacc[2], cacc[3]);
      }
    }

    // ---- out-proj fused with residual + LN sums; h packed bf16 (16 regs) ----
    UB8 cf[4];
#pragma unroll
    for (int ks = 0; ks < 4; ++ks) {
      cf[ks].d[0] = ctx[2 * ks][0];
      cf[ks].d[1] = ctx[2 * ks][1];
      cf[ks].d[2] = ctx[2 * ks + 1][0];
      cf[ks].d[3] = ctx[2 * ks + 1][1];
    }
    float sum = 0.f, sq = 0.f;
    unsigned hp[8][2];
#pragma unroll
    for (int nt = 0; nt < 8; ++nt) {
      bf16x8 wof[4];
#pragma unroll
      for (int ks = 0; ks < 4; ++ks)
        wof[ks] = *(const bf16x8*)(wS + (256 + nt * 16 + c) * 256 + ((ks * 64 + kg * 16) ^ swz));
      f32x4 acc = {0.f, 0.f, 0.f, 0.f};
#pragma unroll
      for (int ks = 0; ks < 4; ++ks)
        acc = __builtin_amdgcn_mfma_f32_16x16x32_bf16(wof[ks], cf[ks].v, acc, 0, 0, 0);
      UB8 xr; xr.v = xcf[nt >> 1].v;
      const int base = 4 * (nt & 1);
#pragma unroll
      for (int j = 0; j < 4; ++j) {
        const float hv = acc[j] + bf2f(xr.u[base + j]);
        sum += hv; sq += hv * hv;
        acc[j] = hv;
      }
      hp[nt][0] = pk2bf(acc[0], acc[1]);
      hp[nt][1] = pk2bf(acc[2], acc[3]);
    }
    sum += __shfl_xor(sum, 16); sq += __shfl_xor(sq, 16);
    sum += __shfl_xor(sum, 32); sq += __shfl_xor(sq, 32);
    const float mu = sum * 0.0078125f;
    const float rs = rsqrtf(sq * 0.0078125f - mu * mu + 1e-5f);
    float* yb = y_out + pair * 2048;
#pragma unroll
    for (int nt = 0; nt < 8; ++nt) {
      const f32x4 g = *(const f32x4*)(gbS + 16 * nt + 4 * kg);
      const f32x4 b = *(const f32x4*)(gbS + 128 + 16 * nt + 4 * kg);
      UB8 hh; hh.d[0] = hp[nt][0]; hh.d[1] = hp[nt][1];
      f32x4 o;
#pragma unroll
      for (int j = 0; j < 4; ++j)
        o[j] = (bf2f(hh.u[j]) - mu) * rs * g[j] + b[j];
      *(f32x4*)(yb + c * 128 + 16 * nt + 4 * kg) = o;
    }
  }
}

extern "C" void kernel_launch(void* const* d_in, const int* in_sizes, int n_in,
                              void* d_out, int out_size, void* d_ws, size_t ws_size,
                              hipStream_t stream) {
  (void)in_sizes; (void)n_in; (void)out_size; (void)ws_size;
  const float* x    = (const float*)d_in[0];
  const float* Wq   = (const float*)d_in[1];
  const float* Wk   = (const float*)d_in[2];
  const float* Wv   = (const float*)d_in[3];
  const float* Wo   = (const float*)d_in[4];
  const float* gam  = (const float*)d_in[5];
  const float* bet  = (const float*)d_in[6];
  const float* relb = (const float*)d_in[7];
  float* y    = (float*)d_out;
  float* attn = y + (size_t)65536 * 1024;
  unsigned short* ws = (unsigned short*)d_ws;

  hipLaunchKernelGGL(prep_kernel, dim3(50), dim3(1024), 0, stream,
                     Wq, Wk, Wv, Wo, gam, bet, ws);
  hipLaunchKernelGGL(wlmha_kernel, dim3(256), dim3(1024), 0, stream,
                     x, ws, relb, y, attn);
}

// Round 9
// 176.973 us; speedup vs baseline: 6.1198x; 6.1163x over previous
//
#include <hip/hip_runtime.h>

typedef __attribute__((ext_vector_type(8))) short bf16x8;
typedef __attribute__((ext_vector_type(4))) float f32x4;
typedef __attribute__((ext_vector_type(2))) unsigned int u32x2;

union UB8 { bf16x8 v; unsigned d[4]; unsigned short u[8]; };

__device__ __forceinline__ float bf2f(unsigned short u) {
  union { unsigned u; float f; } a; a.u = ((unsigned)u) << 16;
  return a.f;
}
// native cast -> v_cvt_pk_bf16_f32 (RNE)
__device__ __forceinline__ unsigned pk2bf(float lo, float hi) {
  union { __bf16 b[2]; unsigned u; } r;
  r.b[0] = (__bf16)lo; r.b[1] = (__bf16)hi;
  return r.u;
}
__device__ __forceinline__ unsigned short f2bf(float f) {  // prep only
  union { float f; unsigned u; } a; a.f = f;
  return (unsigned short)((a.u + 0x7fffu + ((a.u >> 16) & 1u)) >> 16);
}

// ---------------- prep kernel: weights -> bf16, PE table -> f32 (r2-validated) ----------------
// ws (u16 view): [0..8191] Wq, [8192..16383] Wk, [16384..32767] Wv, [32768..49151] Wo
// bytes 98304..102399: PE f32 [8][128]
__global__ void prep_kernel(const float* __restrict__ Wq, const float* __restrict__ Wk,
                            const float* __restrict__ Wv, const float* __restrict__ Wo,
                            unsigned short* __restrict__ ws) {
  const int b = blockIdx.x;
  if (b < 192) {
    int i = b * 256 + threadIdx.x;
    float v;
    if (i < 8192) v = Wq[i];
    else if (i < 16384) v = Wk[i - 8192];
    else if (i < 32768) v = Wv[i - 16384];
    else v = Wo[i - 32768];
    ws[i] = f2bf(v);
  } else {
    float* pe = (float*)(ws + 49152);
#pragma unroll
    for (int k = 0; k < 4; ++k) {
      int e = threadIdx.x * 4 + k;        // 0..1023
      int c = e >> 7, col = e & 127;
      float div = expf(-0.14391156831212727f * (float)(col >> 1));
      float ang = (float)c * div;
      pe[e] = (col & 1) ? cosf(ang) : sinf(ang);
    }
  }
}

// ---------------- fused kernel ----------------
// 256 threads (4 waves); 8 batch rows (M=64 chunk-rows); 8192 blocks.
// LDS 32768 B exact -> 5 blocks/CU:
//   [0..16383]     xcS: xc bf16 [64 rows x 256B] swz   (P1 w; P2 r; P3 ctx w; P4 r)
//   [16384..32767] qkS: Q|K bf16 [64 rows x 256B] swz  (P2 w, P3 r); then h bf16 (P4 w, P5 r)
// V is NEVER staged: V-waves keep their slice in regs (vv) and P3 uses the
// r7-validated shuffle-regroup to build PV fragments.
// Swizzle: byte ^= (row&15)<<4 (rows in-flight span exactly 16 -> 4-way max).
__global__ __launch_bounds__(256, 3)
void wlmha_kernel(const float* __restrict__ x,
                  const unsigned short* __restrict__ wA,   // [256][128] Q|K|V rows
                  const unsigned short* __restrict__ wOb,  // [128][128] Wo
                  const float* __restrict__ peG,
                  const float* __restrict__ gamma,
                  const float* __restrict__ beta,
                  const float* __restrict__ relb,
                  float* __restrict__ y_out,
                  float* __restrict__ attn_out)
{
  const int t   = threadIdx.x;
  const int l   = t & 63;
  const int w   = t >> 6;          // wave 0..3
  const int c   = l & 15;
  const int kg  = l >> 4;          // 0..3
  const int mr0 = t >> 4;          // granule row base (rows mr0+16i)
  const int cgf = t & 15;          // granule col (8-feat groups)
  const int sw0 = (mr0 & 15) << 4;
  const int qc  = l & 7;
  const long b0 = (long)blockIdx.x * 8;

  __shared__ __align__(16) char smem[32768];
  char* xcS = smem;
  char* qkS = smem + 16384;

  // ---------------- P0: issue loads ----------------
  const float* xb = x + b0 * 1024;
  f32x4 xg[4][2];
#pragma unroll
  for (int i = 0; i < 4; ++i) {
    const float* p = xb + (t + 256 * i) * 8;
    xg[i][0] = *(const f32x4*)p;
    xg[i][1] = *(const f32x4*)(p + 4);
  }
  const float* per = peG + (mr0 & 7) * 128 + cgf * 8;
  const f32x4 pe0 = *(const f32x4*)per;
  const f32x4 pe1 = *(const f32x4*)(per + 4);

  // rel-pos bias in regs; P3 head role h = w&1
  float bias[4];
#pragma unroll
  for (int j = 0; j < 4; ++j)
    bias[j] = relb[(w & 1) * 15 + (kg & 1) * 4 + j - qc + 7];

  // QKV weight frags: wave's 64-feature slice (w0:Q, w1:K, w2:V0-63, w3:V64-127)
  bf16x8 wf[4][4];
#pragma unroll
  for (int nb = 0; nb < 4; ++nb) {
    const unsigned short* src = wA + (w * 64 + nb * 16 + c) * 128 + kg * 8;
#pragma unroll
    for (int ks = 0; ks < 4; ++ks) wf[nb][ks] = *(const bf16x8*)(src + ks * 32);
  }

  // ---------------- P1: xc = x + pe -> bf16 xcS (swz) ----------------
#pragma unroll
  for (int i = 0; i < 4; ++i) {
    const int m = mr0 + 16 * i;          // (m&15) == (mr0&15)
    f32x4 a0 = xg[i][0] + pe0;
    f32x4 a1 = xg[i][1] + pe1;
    UB8 fr;
    fr.d[0] = pk2bf(a0[0], a0[1]); fr.d[1] = pk2bf(a0[2], a0[3]);
    fr.d[2] = pk2bf(a1[0], a1[1]); fr.d[3] = pk2bf(a1[2], a1[3]);
    *(bf16x8*)(xcS + m * 256 + ((cgf * 16) ^ sw0)) = fr.v;
  }
  __syncthreads();

  // ---------------- P2: QKV projection via MFMA ----------------
  unsigned vv[4][4][2];   // V-waves only: [nb][mt] -> 4 keys packed (32 VGPR)
#pragma unroll
  for (int mt = 0; mt < 4; ++mt) {
    bf16x8 xf[4];
    const int row = mt * 16 + c;
    const int rsw = (row & 15) << 4;
#pragma unroll
    for (int ks = 0; ks < 4; ++ks)
      xf[ks] = *(const bf16x8*)(xcS + row * 256 + ((ks * 64 + kg * 16) ^ rsw));
    if (w < 2) {
#pragma unroll
      for (int nb = 0; nb < 4; ++nb) {
        f32x4 acc = {0.f, 0.f, 0.f, 0.f};
#pragma unroll
        for (int ks = 0; ks < 4; ++ks)
          acc = __builtin_amdgcn_mfma_f32_16x16x32_bf16(wf[nb][ks], xf[ks], acc, 0, 0, 0);
        u32x2 pk; pk.x = pk2bf(acc[0], acc[1]); pk.y = pk2bf(acc[2], acc[3]);
        const int colb = (w * 128 + nb * 32 + kg * 8) ^ rsw;
        *(u32x2*)(qkS + row * 256 + colb) = pk;
      }
    } else {
#pragma unroll
      for (int nb = 0; nb < 4; ++nb) {
        f32x4 acc = {0.f, 0.f, 0.f, 0.f};
#pragma unroll
        for (int ks = 0; ks < 4; ++ks)
          acc = __builtin_amdgcn_mfma_f32_16x16x32_bf16(xf[ks], wf[nb][ks], acc, 0, 0, 0);
        // lane (c,kg): vfeat (w-2)*64+nb*16+c, keys mt*16+kg*4+{0..3}
        vv[nb][mt][0] = pk2bf(acc[0], acc[1]);
        vv[nb][mt][1] = pk2bf(acc[2], acc[3]);
      }
    }
  }
  // residual snapshot (bf16) before P3 overwrites xcS with ctx
  bf16x8 xcr[4];
#pragma unroll
  for (int i = 0; i < 4; ++i)
    xcr[i] = *(const bf16x8*)(xcS + (mr0 + 16 * i) * 256 + ((cgf * 16) ^ sw0));
  __syncthreads();

  // ---------------- P3: attention (S^T via MFMA; PV from regs via shuffle regroup) ----------------
  bf16x8 wof[2][4];   // Wo frags for P4 (L2-hot)
#pragma unroll
  for (int nt = 0; nt < 2; ++nt) {
    const unsigned short* src = wOb + (w * 32 + nt * 16 + c) * 128 + kg * 8;
#pragma unroll
    for (int ks = 0; ks < 4; ++ks) wof[nt][ks] = *(const bf16x8*)(src + ks * 32);
  }
  {
    const int h = w & 1;
    const bool vmask = ((l >> 5) & 1) == ((l >> 3) & 1);
    const int sA = c + ((kg & 1) << 5);
    const f32x4 zero = {0.f, 0.f, 0.f, 0.f};
#pragma unroll
    for (int T = 0; T < 4; ++T) {
      const int row = T * 16 + c;
      const int sw = (row & 15) << 4;
      bf16x8 kf = *(const bf16x8*)(qkS + row * 256 + ((128 + h * 64 + kg * 16) ^ sw));
      bf16x8 qf = *(const bf16x8*)(qkS + row * 256 + ((h * 64 + kg * 16) ^ sw));
      f32x4 st = __builtin_amdgcn_mfma_f32_16x16x32_bf16(kf, qf, zero, 0, 0, 0);
      float s0[4];
#pragma unroll
      for (int j = 0; j < 4; ++j)
        s0[j] = vmask ? st[j] * 0.17677669529663687f + bias[j] : -1e30f;
      float mx = fmaxf(fmaxf(s0[0], s0[1]), fmaxf(s0[2], s0[3]));
      mx = fmaxf(mx, __shfl_xor(mx, 16));
      mx = fmaxf(mx, __shfl_xor(mx, 32));
      float p[4], sum = 0.f;
#pragma unroll
      for (int j = 0; j < 4; ++j) { p[j] = __expf(s0[j] - mx); sum += p[j]; }
      sum += __shfl_xor(sum, 16);
      sum += __shfl_xor(sum, 32);
      const float inv = 1.0f / sum;
#pragma unroll
      for (int j = 0; j < 4; ++j) p[j] *= inv;

      if (w < 2) {
        if (vmask) {
          float* ap = attn_out + ((b0 + (row >> 3)) * 2 + h) * 64 + qc * 8 + (kg & 1) * 4;
          const f32x4 pv = {p[0], p[1], p[2], p[3]};
          *(f32x4*)ap = pv;
        }
      } else {
        // P^T B-frag (keys 0..15 real, 16..31 zero)
        const unsigned P0 = pk2bf(p[0], p[1]);
        const unsigned P1 = pk2bf(p[2], p[3]);
        UB8 pf;
        pf.d[0] = (unsigned)__shfl((int)P0, sA);
        pf.d[1] = (unsigned)__shfl((int)P1, sA);
        pf.d[2] = (unsigned)__shfl((int)P0, sA + 16);
        pf.d[3] = (unsigned)__shfl((int)P1, sA + 16);
        if (kg >= 2) { pf.d[0] = 0; pf.d[1] = 0; pf.d[2] = 0; pf.d[3] = 0; }
        // PV: vt frags from vv regs (r7-validated regroup); ctx -> xcS
#pragma unroll
        for (int nb = 0; nb < 4; ++nb) {
          UB8 vt;
          vt.d[0] = (unsigned)__shfl((int)vv[nb][T][0], sA);
          vt.d[1] = (unsigned)__shfl((int)vv[nb][T][1], sA);
          vt.d[2] = (unsigned)__shfl((int)vv[nb][T][0], sA + 16);
          vt.d[3] = (unsigned)__shfl((int)vv[nb][T][1], sA + 16);
          if (kg >= 2) { vt.d[0] = 0; vt.d[1] = 0; vt.d[2] = 0; vt.d[3] = 0; }
          const f32x4 cacc = __builtin_amdgcn_mfma_f32_16x16x32_bf16(vt.v, pf.v, zero, 0, 0, 0);
          // lane (c,kg): ctx feats (w-2)*64+nb*16+kg*4+{0,1,2,3}, qrow = row
          u32x2 pk; pk.x = pk2bf(cacc[0], cacc[1]); pk.y = pk2bf(cacc[2], cacc[3]);
          const int fb = ((w - 2) * 128 + nb * 32 + kg * 8) ^ sw;
          *(u32x2*)(xcS + row * 256 + fb) = pk;
        }
      }
    }
  }
  __syncthreads();

  // ---------------- P4: out = ctx @ Wo^T -> h bf16 into qkS ----------------
#pragma unroll
  for (int mt = 0; mt < 4; ++mt) {
    bf16x8 cf[4];
    const int row = mt * 16 + c;
    const int rsw = (row & 15) << 4;
#pragma unroll
    for (int ks = 0; ks < 4; ++ks)
      cf[ks] = *(const bf16x8*)(xcS + row * 256 + ((ks * 64 + kg * 16) ^ rsw));
#pragma unroll
    for (int nt = 0; nt < 2; ++nt) {
      f32x4 acc = {0.f, 0.f, 0.f, 0.f};
#pragma unroll
      for (int ks = 0; ks < 4; ++ks)
        acc = __builtin_amdgcn_mfma_f32_16x16x32_bf16(wof[nt][ks], cf[ks], acc, 0, 0, 0);
      // lane (c,kg): h feats w*32+nt*16+kg*4+{0..3} for qrow=row
      u32x2 pk; pk.x = pk2bf(acc[0], acc[1]); pk.y = pk2bf(acc[2], acc[3]);
      const int colb = (w * 64 + nt * 32 + kg * 8) ^ rsw;
      *(u32x2*)(qkS + row * 256 + colb) = pk;
    }
  }
  __syncthreads();

  // ---------------- P5: residual(bf16 regs) + LN + y store ----------------
  {
    const f32x4 gm0 = *(const f32x4*)(gamma + cgf * 8);
    const f32x4 gm1 = *(const f32x4*)(gamma + cgf * 8 + 4);
    const f32x4 bt0 = *(const f32x4*)(beta + cgf * 8);
    const f32x4 bt1 = *(const f32x4*)(beta + cgf * 8 + 4);
    float* yb = y_out + b0 * 1024;
#pragma unroll
    for (int i = 0; i < 4; ++i) {
      const int m = mr0 + 16 * i;
      UB8 hh; hh.v = *(const bf16x8*)(qkS + m * 256 + ((cgf * 16) ^ sw0));
      UB8 xr; xr.v = xcr[i];
      float hv[8];
      float sum = 0.f, sq = 0.f;
#pragma unroll
      for (int j = 0; j < 8; ++j) {
        hv[j] = bf2f(hh.u[j]) + bf2f(xr.u[j]);
        sum += hv[j]; sq += hv[j] * hv[j];
      }
#pragma unroll
      for (int d = 1; d < 16; d <<= 1) {
        sum += __shfl_xor(sum, d);
        sq  += __shfl_xor(sq, d);
      }
      const float mu = sum * 0.0078125f;
      const float rs = rsqrtf(sq * 0.0078125f - mu * mu + 1e-5f);
      f32x4 o0, o1;
#pragma unroll
      for (int j = 0; j < 4; ++j) {
        o0[j] = (hv[j]     - mu) * rs * gm0[j] + bt0[j];
        o1[j] = (hv[4 + j] - mu) * rs * gm1[j] + bt1[j];
      }
      const int g = t + 256 * i;
      *(f32x4*)(yb + g * 8) = o0;
      *(f32x4*)(yb + g * 8 + 4) = o1;
    }
  }
}

extern "C" void kernel_launch(void* const* d_in, const int* in_sizes, int n_in,
                              void* d_out, int out_size, void* d_ws, size_t ws_size,
                              hipStream_t stream) {
  (void)in_sizes; (void)n_in; (void)out_size; (void)ws_size;
  const float* x    = (const float*)d_in[0];
  const float* Wq   = (const float*)d_in[1];
  const float* Wk   = (const float*)d_in[2];
  const float* Wv   = (const float*)d_in[3];
  const float* Wo   = (const float*)d_in[4];
  const float* gam  = (const float*)d_in[5];
  const float* bet  = (const float*)d_in[6];
  const float* relb = (const float*)d_in[7];
  float* y    = (float*)d_out;
  float* attn = y + (size_t)65536 * 1024;
  unsigned short* ws = (unsigned short*)d_ws;
  const float* peG = (const float*)(ws + 49152);

  hipLaunchKernelGGL(prep_kernel, dim3(193), dim3(256), 0, stream, Wq, Wk, Wv, Wo, ws);
  hipLaunchKernelGGL(wlmha_kernel, dim3(8192), dim3(256), 0, stream,
                     x, ws, ws + 32768, peG, gam, bet, relb, y, attn);
}

// Round 10
// 175.822 us; speedup vs baseline: 6.1599x; 1.0065x over previous
//
#include <hip/hip_runtime.h>

typedef __attribute__((ext_vector_type(8))) short bf16x8;
typedef __attribute__((ext_vector_type(4))) float f32x4;
typedef __attribute__((ext_vector_type(2))) float f32x2;
typedef __attribute__((ext_vector_type(2))) unsigned int u32x2;

union UB8 { bf16x8 v; unsigned d[4]; unsigned short u[8]; };

__device__ __forceinline__ float bf2f(unsigned short u) {
  union { unsigned u; float f; } a; a.u = ((unsigned)u) << 16;
  return a.f;
}
// native cast -> v_cvt_pk_bf16_f32 (RNE)
__device__ __forceinline__ unsigned pk2bf(float lo, float hi) {
  union { __bf16 b[2]; unsigned u; } r;
  r.b[0] = (__bf16)lo; r.b[1] = (__bf16)hi;
  return r.u;
}
__device__ __forceinline__ unsigned short f2bf(float f) {  // prep only
  union { float f; unsigned u; } a; a.f = f;
  return (unsigned short)((a.u + 0x7fffu + ((a.u >> 16) & 1u)) >> 16);
}

// ---------------- prep kernel: weights -> bf16, PE table -> f32 (validated) ----------------
// ws (u16): [0..8191] Wq, [8192..16383] Wk, [16384..32767] Wv, [32768..49151] Wo
// bytes 98304..102399: PE f32 [8][128]
__global__ void prep_kernel(const float* __restrict__ Wq, const float* __restrict__ Wk,
                            const float* __restrict__ Wv, const float* __restrict__ Wo,
                            unsigned short* __restrict__ ws) {
  const int b = blockIdx.x;
  if (b < 192) {
    int i = b * 256 + threadIdx.x;
    float v;
    if (i < 8192) v = Wq[i];
    else if (i < 16384) v = Wk[i - 8192];
    else if (i < 32768) v = Wv[i - 16384];
    else v = Wo[i - 32768];
    ws[i] = f2bf(v);
  } else {
    float* pe = (float*)(ws + 49152);
#pragma unroll
    for (int k = 0; k < 4; ++k) {
      int e = threadIdx.x * 4 + k;        // 0..1023
      int c = e >> 7, col = e & 127;
      float div = expf(-0.14391156831212727f * (float)(col >> 1));
      float ang = (float)c * div;
      pe[e] = (col & 1) ? cosf(ang) : sinf(ang);
    }
  }
}

// ---------------- fused kernel ----------------
// 256 threads (4 waves); 8 batch rows (M=64); 8192 blocks. LDS 32768B:
//   [0..16383]     xcS: xc bf16 [64 x 256B] swz (P1 w; P2 r + snapshot; P3 ctx w; P4 r)
//   [16384..32767] qkS: Q|K bf16 [64 x 256B] swz (P2 w, P3 r); first 2KB = LN sums (P4 w, P5 r)
// Balanced waves: each wave owns 32 QK-feats AND 32 V-feats (V in regs, no staging);
// every wave computes softmax for its head (w>>1) and PV for its vfeat slice.
// h stays in f32 regs through P4/P5 (no LDS round-trip); LN via 2KB partials.
// Swizzle everywhere: byte ^= (row&15)<<4; row&15 == c for all phases.
__global__ __launch_bounds__(256, 3)
void wlmha_kernel(const float* __restrict__ x,
                  const unsigned short* __restrict__ wA,   // [256][128] Q|K|V rows
                  const unsigned short* __restrict__ wOb,  // [128][128] Wo
                  const float* __restrict__ peG,
                  const float* __restrict__ gamma,
                  const float* __restrict__ beta,
                  const float* __restrict__ relb,
                  float* __restrict__ y_out,
                  float* __restrict__ attn_out)
{
  const int t   = threadIdx.x;
  const int l   = t & 63;
  const int w   = t >> 6;          // wave 0..3
  const int c   = l & 15;
  const int kg  = l >> 4;          // 0..3
  const int mr0 = t >> 4;          // 0..15 granule row base
  const int cgf = t & 15;
  const int sw0 = mr0 << 4;
  const int qc  = c & 7;
  const int rsw = c << 4;          // swizzle for all row = mt*16+c accesses
  const long b0 = (long)blockIdx.x * 8;

  __shared__ __align__(16) char smem[32768];
  char* xcS = smem;
  char* qkS = smem + 16384;

  // ---------------- P0: issue loads ----------------
  const float* xb = x + b0 * 1024;
  f32x4 xg[4][2];
#pragma unroll
  for (int i = 0; i < 4; ++i) {
    const float* p = xb + (t + 256 * i) * 8;
    xg[i][0] = *(const f32x4*)p;
    xg[i][1] = *(const f32x4*)(p + 4);
  }
  const float* per = peG + (mr0 & 7) * 128 + cgf * 8;
  const f32x4 pe0 = *(const f32x4*)per;
  const f32x4 pe1 = *(const f32x4*)(per + 4);

  const int h2 = w >> 1;           // this wave's head for P3
  float bias[4];
#pragma unroll
  for (int j = 0; j < 4; ++j)
    bias[j] = relb[h2 * 15 + (kg & 1) * 4 + j - qc + 7];

  // wave's 32 QK-feats (w0,w1: Q; w2,w3: K) + 32 V-feats
  bf16x8 wf[2][4], wv[2][4];
#pragma unroll
  for (int nb = 0; nb < 2; ++nb) {
    const unsigned short* sQK = wA + (w * 32 + nb * 16 + c) * 128 + kg * 8;
    const unsigned short* sV  = wA + (128 + w * 32 + nb * 16 + c) * 128 + kg * 8;
#pragma unroll
    for (int ks = 0; ks < 4; ++ks) {
      wf[nb][ks] = *(const bf16x8*)(sQK + ks * 32);
      wv[nb][ks] = *(const bf16x8*)(sV + ks * 32);
    }
  }

  // ---------------- P1: xc = x + pe -> bf16 xcS (swz) ----------------
#pragma unroll
  for (int i = 0; i < 4; ++i) {
    const int m = mr0 + 16 * i;
    f32x4 a0 = xg[i][0] + pe0;
    f32x4 a1 = xg[i][1] + pe1;
    UB8 fr;
    fr.d[0] = pk2bf(a0[0], a0[1]); fr.d[1] = pk2bf(a0[2], a0[3]);
    fr.d[2] = pk2bf(a1[0], a1[1]); fr.d[3] = pk2bf(a1[2], a1[3]);
    *(bf16x8*)(xcS + m * 256 + ((cgf * 16) ^ sw0)) = fr.v;
  }
  __syncthreads();

  // ---------------- P2: QKV via MFMA; Q|K -> qkS, V -> regs; residual snapshot ----------------
  unsigned vv[2][4][2];     // [nb][mt] keys packed (vfeat = w*32+nb*16+c)
#pragma unroll
  for (int mt = 0; mt < 4; ++mt) {
    bf16x8 xf[4];
    const int row = mt * 16 + c;
#pragma unroll
    for (int ks = 0; ks < 4; ++ks)
      xf[ks] = *(const bf16x8*)(xcS + row * 256 + ((ks * 64 + kg * 16) ^ rsw));
#pragma unroll
    for (int nb = 0; nb < 2; ++nb) {
      f32x4 acc = {0.f, 0.f, 0.f, 0.f};
#pragma unroll
      for (int ks = 0; ks < 4; ++ks)
        acc = __builtin_amdgcn_mfma_f32_16x16x32_bf16(wf[nb][ks], xf[ks], acc, 0, 0, 0);
      u32x2 pk; pk.x = pk2bf(acc[0], acc[1]); pk.y = pk2bf(acc[2], acc[3]);
      *(u32x2*)(qkS + row * 256 + ((w * 64 + nb * 32 + kg * 8) ^ rsw)) = pk;
    }
#pragma unroll
    for (int nb = 0; nb < 2; ++nb) {
      f32x4 acc = {0.f, 0.f, 0.f, 0.f};
#pragma unroll
      for (int ks = 0; ks < 4; ++ks)
        acc = __builtin_amdgcn_mfma_f32_16x16x32_bf16(xf[ks], wv[nb][ks], acc, 0, 0, 0);
      vv[nb][mt][0] = pk2bf(acc[0], acc[1]);
      vv[nb][mt][1] = pk2bf(acc[2], acc[3]);
    }
  }
  // residual snapshot in P4 layout: rows mt*16+c, feats w*32+nt*16+kg*4+{0..3}
  unsigned xr[4][2][2];
#pragma unroll
  for (int mt = 0; mt < 4; ++mt)
#pragma unroll
    for (int nt = 0; nt < 2; ++nt) {
      u32x2 rr = *(const u32x2*)(xcS + (mt * 16 + c) * 256 + ((w * 64 + nt * 32 + kg * 8) ^ rsw));
      xr[mt][nt][0] = rr.x; xr[mt][nt][1] = rr.y;
    }
  __syncthreads();

  // ---------------- P3: attention (balanced); ctx -> xcS ----------------
  bf16x8 wof[2][4];   // Wo rows w*32+nt*16+c (for P4)
#pragma unroll
  for (int nt = 0; nt < 2; ++nt) {
    const unsigned short* src = wOb + (w * 32 + nt * 16 + c) * 128 + kg * 8;
#pragma unroll
    for (int ks = 0; ks < 4; ++ks) wof[nt][ks] = *(const bf16x8*)(src + ks * 32);
  }
  // gamma/beta for this thread's P5 feats (L2-hot)
  f32x4 gm[2], bt[2];
#pragma unroll
  for (int nt = 0; nt < 2; ++nt) {
    gm[nt] = *(const f32x4*)(gamma + w * 32 + nt * 16 + kg * 4);
    bt[nt] = *(const f32x4*)(beta  + w * 32 + nt * 16 + kg * 4);
  }
  {
    const bool vmask = ((l >> 5) & 1) == ((l >> 3) & 1);
    const int sA = c + ((kg & 1) << 5);
    const f32x4 zero = {0.f, 0.f, 0.f, 0.f};
#pragma unroll
    for (int T = 0; T < 4; ++T) {
      const int row = T * 16 + c;
      bf16x8 kf = *(const bf16x8*)(qkS + row * 256 + ((128 + h2 * 64 + kg * 16) ^ rsw));
      bf16x8 qf = *(const bf16x8*)(qkS + row * 256 + ((h2 * 64 + kg * 16) ^ rsw));
      f32x4 st = __builtin_amdgcn_mfma_f32_16x16x32_bf16(kf, qf, zero, 0, 0, 0);
      float s0[4];
#pragma unroll
      for (int j = 0; j < 4; ++j)
        s0[j] = vmask ? st[j] * 0.17677669529663687f + bias[j] : -1e30f;
      float mx = fmaxf(fmaxf(s0[0], s0[1]), fmaxf(s0[2], s0[3]));
      mx = fmaxf(mx, __shfl_xor(mx, 16));
      mx = fmaxf(mx, __shfl_xor(mx, 32));
      float p[4], sum = 0.f;
#pragma unroll
      for (int j = 0; j < 4; ++j) { p[j] = __expf(s0[j] - mx); sum += p[j]; }
      sum += __shfl_xor(sum, 16);
      sum += __shfl_xor(sum, 32);
      const float inv = 1.0f / sum;
#pragma unroll
      for (int j = 0; j < 4; ++j) p[j] *= inv;

      if ((w & 1) == 0 && vmask) {   // w0 stores head0, w2 stores head1
        float* ap = attn_out + ((b0 + (row >> 3)) * 2 + h2) * 64 + qc * 8 + (kg & 1) * 4;
        const f32x4 pv = {p[0], p[1], p[2], p[3]};
        *(f32x4*)ap = pv;
      }

      // P^T B-frag (keys 0..15 real, 16..31 zero)
      const unsigned P0 = pk2bf(p[0], p[1]);
      const unsigned P1 = pk2bf(p[2], p[3]);
      UB8 pf;
      pf.d[0] = (unsigned)__shfl((int)P0, sA);
      pf.d[1] = (unsigned)__shfl((int)P1, sA);
      pf.d[2] = (unsigned)__shfl((int)P0, sA + 16);
      pf.d[3] = (unsigned)__shfl((int)P1, sA + 16);
      if (kg >= 2) { pf.d[0] = 0; pf.d[1] = 0; pf.d[2] = 0; pf.d[3] = 0; }

      // PV for this wave's 32 vfeats; ctx -> xcS (disjoint cols per wave)
#pragma unroll
      for (int nb = 0; nb < 2; ++nb) {
        UB8 vt;
        vt.d[0] = (unsigned)__shfl((int)vv[nb][T][0], sA);
        vt.d[1] = (unsigned)__shfl((int)vv[nb][T][1], sA);
        vt.d[2] = (unsigned)__shfl((int)vv[nb][T][0], sA + 16);
        vt.d[3] = (unsigned)__shfl((int)vv[nb][T][1], sA + 16);
        if (kg >= 2) { vt.d[0] = 0; vt.d[1] = 0; vt.d[2] = 0; vt.d[3] = 0; }
        const f32x4 cacc = __builtin_amdgcn_mfma_f32_16x16x32_bf16(vt.v, pf.v, zero, 0, 0, 0);
        u32x2 pk; pk.x = pk2bf(cacc[0], cacc[1]); pk.y = pk2bf(cacc[2], cacc[3]);
        *(u32x2*)(xcS + row * 256 + ((w * 64 + nb * 32 + kg * 8) ^ rsw)) = pk;
      }
    }
  }
  __syncthreads();

  // ---------------- P4: out-proj -> h in regs; residual; LN partials -> qkS[0..2KB) ----------------
  f32x4 hreg[4][2];
#pragma unroll
  for (int mt = 0; mt < 4; ++mt) {
    bf16x8 cf[4];
    const int row = mt * 16 + c;
#pragma unroll
    for (int ks = 0; ks < 4; ++ks)
      cf[ks] = *(const bf16x8*)(xcS + row * 256 + ((ks * 64 + kg * 16) ^ rsw));
    float s = 0.f, q = 0.f;
#pragma unroll
    for (int nt = 0; nt < 2; ++nt) {
      f32x4 acc = {0.f, 0.f, 0.f, 0.f};
#pragma unroll
      for (int ks = 0; ks < 4; ++ks)
        acc = __builtin_amdgcn_mfma_f32_16x16x32_bf16(wof[nt][ks], cf[ks], acc, 0, 0, 0);
      UB8 rr; rr.d[0] = xr[mt][nt][0]; rr.d[1] = xr[mt][nt][1];
#pragma unroll
      for (int j = 0; j < 4; ++j) {
        acc[j] += bf2f(rr.u[j]);
        s += acc[j]; q += acc[j] * acc[j];
      }
      hreg[mt][nt] = acc;
    }
    // reduce over kg (lanes with same c): partial for (row, wave)
    s += __shfl_xor(s, 16); q += __shfl_xor(q, 16);
    s += __shfl_xor(s, 32); q += __shfl_xor(q, 32);
    if (kg == 0) {
      f32x2 pr; pr.x = s; pr.y = q;
      *(f32x2*)(qkS + row * 32 + w * 8) = pr;
    }
  }
  __syncthreads();

  // ---------------- P5: LN from partials + store y from regs ----------------
  {
    float* yb = y_out + b0 * 1024;
#pragma unroll
    for (int mt = 0; mt < 4; ++mt) {
      const int row = mt * 16 + c;
      const f32x4 sa = *(const f32x4*)(qkS + row * 32);
      const f32x4 sb = *(const f32x4*)(qkS + row * 32 + 16);
      const float s = sa[0] + sa[2] + sb[0] + sb[2];
      const float q = sa[1] + sa[3] + sb[1] + sb[3];
      const float mu = s * 0.0078125f;
      const float rs = rsqrtf(q * 0.0078125f - mu * mu + 1e-5f);
#pragma unroll
      for (int nt = 0; nt < 2; ++nt) {
        f32x4 o;
#pragma unroll
        for (int j = 0; j < 4; ++j)
          o[j] = (hreg[mt][nt][j] - mu) * rs * gm[nt][j] + bt[nt][j];
        *(f32x4*)(yb + row * 128 + w * 32 + nt * 16 + kg * 4) = o;
      }
    }
  }
}

extern "C" void kernel_launch(void* const* d_in, const int* in_sizes, int n_in,
                              void* d_out, int out_size, void* d_ws, size_t ws_size,
                              hipStream_t stream) {
  (void)in_sizes; (void)n_in; (void)out_size; (void)ws_size;
  const float* x    = (const float*)d_in[0];
  const float* Wq   = (const float*)d_in[1];
  const float* Wk   = (const float*)d_in[2];
  const float* Wv   = (const float*)d_in[3];
  const float* Wo   = (const float*)d_in[4];
  const float* gam  = (const float*)d_in[5];
  const float* bet  = (const float*)d_in[6];
  const float* relb = (const float*)d_in[7];
  float* y    = (float*)d_out;
  float* attn = y + (size_t)65536 * 1024;
  unsigned short* ws = (unsigned short*)d_ws;
  const float* peG = (const float*)(ws + 49152);

  hipLaunchKernelGGL(prep_kernel, dim3(193), dim3(256), 0, stream, Wq, Wk, Wv, Wo, ws);
  hipLaunchKernelGGL(wlmha_kernel, dim3(8192), dim3(256), 0, stream,
                     x, ws, ws + 32768, peG, gam, bet, relb, y, attn);
}